// Round 1
// baseline (60.083 us; speedup 1.0000x reference)
//
#include <hip/hip_runtime.h>

// Sprecher network layer: out[b,o] = sum_i alfa[i] * spline_i(X[b,i] + qa[o])
// B=512, I=256, O=512, G=7, grid [-1,7], h=4/3 -> t = 0.75*(v+1), idx=floor(t) in [0,5].
//
// Key transforms:
//  * per-segment affine: alfa*s = P[i][k] + Q[i][k]*t   (Q=alfa*(c1-c0), P=alfa*c0-Q*k)
//  * channel compaction: alfa[i] ~ 10^-i underflows to 0 for i>~45; skip |alfa|<=1e-20
//    (error bound ~1e-17, threshold 4.5e-2)
//  * wave = 64 consecutive o -> t span 0.53 -> <=2 distinct idx per wave -> conflict-free
//    broadcast LDS gathers.

#define B_ 512
#define I_ 256
#define O_ 512
#define G_ 7

__global__ __launch_bounds__(256) void spreecher_kernel(
    const float* __restrict__ X,      // (B, I)
    const float* __restrict__ coeffs, // (I, G)
    const float* __restrict__ alfa,   // (1, I, O) but alfa[0,i,o] == aux[i]
    const float* __restrict__ qa,     // (O,)
    float* __restrict__ out)          // (B, O)
{
    __shared__ float2 tab[I_ * 6];   // (P,Q) per active channel slot x segment
    __shared__ float  xs[I_];        // compacted X[b, i] per active slot
    __shared__ int    sIdx[I_];      // active slot -> original channel
    __shared__ int    sCnt;

    const int tid    = threadIdx.x;
    const int b      = blockIdx.x >> 1;
    const int ochunk = blockIdx.x & 1;

    if (tid == 0) sCnt = 0;
    __syncthreads();

    // Phase A: channel compaction (blockDim == I_ == 256, one thread per channel)
    {
        const int i = tid;
        const float aux = alfa[i * O_];   // column o=0 of the broadcast alfa
        if (fabsf(aux) > 1e-20f) {
            const int pos = atomicAdd(&sCnt, 1);
            sIdx[pos] = i;
            xs[pos]   = X[b * I_ + i];
        }
    }
    __syncthreads();
    const int nAct = sCnt;

    // Phase B: build affine segment table for active channels
    for (int e = tid; e < nAct * 6; e += 256) {
        const int s = e / 6;
        const int k = e - s * 6;
        const int i = sIdx[s];
        const float aux = alfa[i * O_];
        const float c0  = coeffs[i * G_ + k];
        const float c1  = coeffs[i * G_ + k + 1];
        const float Q   = aux * (c1 - c0);
        const float P   = fmaf(-Q, (float)k, aux * c0);
        tab[s * 6 + k] = make_float2(P, Q);
    }
    __syncthreads();

    // Main loop: each thread owns one (b, o); lanes = consecutive o.
    const int   o  = (ochunk << 8) | tid;
    const float tq = fmaf(qa[o], 0.75f, 0.75f);   // t = 0.75*x + tq

    float sumP = 0.f, sumQ = 0.f;
    #pragma unroll 4
    for (int s = 0; s < nAct; ++s) {
        const float t = fmaf(xs[s], 0.75f, tq);
        int idx = (int)t;            // t >= 0.75 for valid inputs
        idx = idx > 0 ? idx : 0;     // safety clamps (never bind for the given domain)
        idx = idx < 5 ? idx : 5;
        const float2 pq = tab[s * 6 + idx];
        sumP += pq.x;
        sumQ  = fmaf(pq.y, t, sumQ);
    }
    out[b * O_ + o] = sumP + sumQ;
}

extern "C" void kernel_launch(void* const* d_in, const int* in_sizes, int n_in,
                              void* d_out, int out_size, void* d_ws, size_t ws_size,
                              hipStream_t stream) {
    const float* X      = (const float*)d_in[0];
    const float* coeffs = (const float*)d_in[1];
    const float* alfa   = (const float*)d_in[2];
    const float* qa     = (const float*)d_in[3];
    float* out = (float*)d_out;

    dim3 grid(B_ * (O_ / 256));  // 1024 blocks: (b, o-chunk)
    dim3 block(256);
    spreecher_kernel<<<grid, block, 0, stream>>>(X, coeffs, alfa, qa, out);
}